// Round 13
// baseline (1150.204 us; speedup 1.0000x reference)
//
#include <hip/hip_runtime.h>
#include <hip/hip_bf16.h>

#define NN 50000
#define EE 800000
#define GG 64
#define RR 3
#define METAD 38
#define NSEG (RR*NN)
#define EPSV 1e-5f

typedef __bf16 bf_t;
typedef __attribute__((ext_vector_type(8))) __bf16 bf16x8;
typedef __attribute__((ext_vector_type(4))) __bf16 bf16x4;
typedef __attribute__((ext_vector_type(2))) __bf16 bf16x2;
typedef __attribute__((ext_vector_type(4))) float f32x4;

__device__ __forceinline__ float loadf(const void* p, size_t i, int flag){
  return flag ? ((const float*)p)[i] : (float)(((const bf_t*)p)[i]);
}

// ---------------- dtype detector: fp32 (1) vs bf16 (0) ----------------
__global__ __launch_bounds__(256) void detect_kernel(const void* __restrict__ xraw,
                                                     int* __restrict__ flag){
  __shared__ int found;
  if (threadIdx.x == 0) found = 0;
  __syncthreads();
  const unsigned short* u = (const unsigned short*)xraw;
  for (int i = threadIdx.x; i < 65536; i += 256){
    int e = (u[i] >> 7) & 0xFF;
    if (e >= 0xF0) found = 1;
  }
  __syncthreads();
  if (threadIdx.x == 0) *flag = found;
}

// ---------------- merged small-param convert ----------------
struct CvtJobs {
  const void* src[17];
  float* dst[17];
  int n[17];
};

__global__ __launch_bounds__(256) void cvt_many(CvtJobs j, const int* __restrict__ flag){
  int job = blockIdx.y;
  int i = blockIdx.x*256 + threadIdx.x;
  if (i < j.n[job]) j.dst[job][i] = loadf(j.src[job], i, *flag);
}

// ---------------- pack weights: WbT[o][r*DP+i] = W[r][i][o] (bf16, zero-padded) ----------------
__global__ __launch_bounds__(256) void pack_w(const void* __restrict__ W,
                                              const void* __restrict__ R,
                                              bf_t* __restrict__ out,
                                              int D, int O, int dplog,
                                              const int* __restrict__ flag){
  int id = blockIdx.x*256 + threadIdx.x;
  int DP4 = 1 << (dplog + 2);
  int o = id >> (dplog + 2);
  int k = id & (DP4 - 1);
  int r = k >> dplog;
  int i = k & ((1 << dplog) - 1);
  float v = 0.f;
  int fl = *flag;
  if (i < D && o < O){
    if (r < 3) v = loadf(W, ((size_t)r*D + i)*O + o, fl);
    else       v = loadf(R, (size_t)i*O + o, fl);
  }
  out[(size_t)o*DP4 + k] = (bf_t)v;
}

// ---------------- CSR build ----------------
__global__ __launch_bounds__(256) void counti_kernel(const int* __restrict__ ei,
                                                     const int* __restrict__ et,
                                                     int* __restrict__ cnt){
  int e = blockIdx.x*256 + threadIdx.x;
  if (e < EE) atomicAdd(&cnt[et[e]*NN + ei[EE + e]], 1);
}

__global__ __launch_bounds__(256) void rcnt_kernel(const int* __restrict__ cnt,
                                                   float* __restrict__ rcnt){
  int i = blockIdx.x*256 + threadIdx.x;
  if (i < NSEG) rcnt[i] = 1.0f / (float)max(cnt[i], 1);
}

__global__ __launch_bounds__(256) void scan1_kernel(const int* __restrict__ cnt,
                                                    int* __restrict__ segoff,
                                                    int* __restrict__ bsums){
  __shared__ int sh[256];
  int i = blockIdx.x*256 + threadIdx.x;
  int v = (i < NSEG) ? cnt[i] : 0;
  sh[threadIdx.x] = v;
  __syncthreads();
  for (int off = 1; off < 256; off <<= 1){
    int t = 0;
    if (threadIdx.x >= off) t = sh[threadIdx.x - off];
    __syncthreads();
    if (threadIdx.x >= off) sh[threadIdx.x] += t;
    __syncthreads();
  }
  if (i < NSEG) segoff[i] = sh[threadIdx.x] - v;
  if (threadIdx.x == 255) bsums[blockIdx.x] = sh[255];
}

__global__ __launch_bounds__(256) void scan2_kernel(int* __restrict__ bsums, int nb){
  __shared__ int sh[256];
  __shared__ int carry;
  if (threadIdx.x == 0) carry = 0;
  __syncthreads();
  for (int base = 0; base < nb; base += 256){
    int i = base + threadIdx.x;
    int v = (i < nb) ? bsums[i] : 0;
    sh[threadIdx.x] = v;
    __syncthreads();
    for (int off = 1; off < 256; off <<= 1){
      int t = 0;
      if (threadIdx.x >= off) t = sh[threadIdx.x - off];
      __syncthreads();
      if (threadIdx.x >= off) sh[threadIdx.x] += t;
      __syncthreads();
    }
    if (i < nb) bsums[i] = sh[threadIdx.x] - v + carry;
    __syncthreads();
    if (threadIdx.x == 0) carry += sh[255];
    __syncthreads();
  }
}

__global__ __launch_bounds__(256) void scan3_kernel(int* __restrict__ segoff,
                                                    const int* __restrict__ bsums){
  int i = blockIdx.x*256 + threadIdx.x;
  if (i < NSEG) segoff[i] += bsums[blockIdx.x];
  if (i == 0) segoff[NSEG] = EE;
}

__global__ __launch_bounds__(256) void curinit_kernel(const int* __restrict__ segoff,
                                                      int* __restrict__ cursor){
  int i = blockIdx.x*256 + threadIdx.x;
  if (i < NSEG) cursor[i] = segoff[i];
}

__global__ __launch_bounds__(256) void place_kernel(const int* __restrict__ ei,
                                                    const int* __restrict__ et,
                                                    int* __restrict__ cursor,
                                                    int* __restrict__ srcs){
  int e = blockIdx.x*256 + threadIdx.x;
  if (e < EE){
    int seg = et[e]*NN + ei[EE + e];
    int pos = atomicAdd(&cursor[seg], 1);
    srcs[pos] = ei[e];
  }
}

// ---------------- x -> Ab slice3 (layer0, D=DP=128, lda=512) ----------------
__global__ __launch_bounds__(128) void cvt_x(const void* __restrict__ x,
                                             bf_t* __restrict__ Ab,
                                             const int* __restrict__ flag){
  int d = blockIdx.x, t = threadIdx.x;
  Ab[(size_t)d*512 + 384 + t] = (bf_t)loadf(x, (size_t)d*128 + t, *flag);
}

// ------- wave-per-segment CSR gather mean: Y[d][r*DP+c] = rcnt * sum h[src][c] -------
template<int DP>
__global__ __launch_bounds__(256) void aggregate_wave(const bf_t* __restrict__ Ab, int lda,
                                                      const int* __restrict__ segoff,
                                                      const int* __restrict__ srcs,
                                                      const float* __restrict__ rcnt,
                                                      bf_t* __restrict__ out){
  int wid = (blockIdx.x*256 + threadIdx.x) >> 6;
  if (wid >= NSEG) return;
  int lane = threadIdx.x & 63;
  int r = wid / NN;
  int d = wid - r*NN;
  int s0 = segoff[wid], s1 = segoff[wid + 1];
  const bf_t* in = Ab + 3*DP;

  if (DP == 256){
    float a0=0.f, a1=0.f, a2=0.f, a3=0.f;
    const int off = lane*4;
    int e = s0;
    for (; e + 4 <= s1; e += 4){
      int sA = srcs[e], sB = srcs[e+1], sC = srcs[e+2], sD = srcs[e+3];
      uint2 vA = *(const uint2*)(in + (size_t)sA*lda + off);
      uint2 vB = *(const uint2*)(in + (size_t)sB*lda + off);
      uint2 vC = *(const uint2*)(in + (size_t)sC*lda + off);
      uint2 vD = *(const uint2*)(in + (size_t)sD*lda + off);
      a0 += __uint_as_float(vA.x << 16); a1 += __uint_as_float(vA.x & 0xFFFF0000u);
      a2 += __uint_as_float(vA.y << 16); a3 += __uint_as_float(vA.y & 0xFFFF0000u);
      a0 += __uint_as_float(vB.x << 16); a1 += __uint_as_float(vB.x & 0xFFFF0000u);
      a2 += __uint_as_float(vB.y << 16); a3 += __uint_as_float(vB.y & 0xFFFF0000u);
      a0 += __uint_as_float(vC.x << 16); a1 += __uint_as_float(vC.x & 0xFFFF0000u);
      a2 += __uint_as_float(vC.y << 16); a3 += __uint_as_float(vC.y & 0xFFFF0000u);
      a0 += __uint_as_float(vD.x << 16); a1 += __uint_as_float(vD.x & 0xFFFF0000u);
      a2 += __uint_as_float(vD.y << 16); a3 += __uint_as_float(vD.y & 0xFFFF0000u);
    }
    for (; e < s1; ++e){
      int s = srcs[e];
      uint2 v = *(const uint2*)(in + (size_t)s*lda + off);
      a0 += __uint_as_float(v.x << 16); a1 += __uint_as_float(v.x & 0xFFFF0000u);
      a2 += __uint_as_float(v.y << 16); a3 += __uint_as_float(v.y & 0xFFFF0000u);
    }
    float rc = rcnt[wid];
    bf16x4 o = {(bf_t)(a0*rc), (bf_t)(a1*rc), (bf_t)(a2*rc), (bf_t)(a3*rc)};
    *(bf16x4*)(out + (size_t)d*lda + r*DP + off) = o;
  } else {
    float a0=0.f, a1=0.f;
    const int off = lane*2;
    int e = s0;
    for (; e + 4 <= s1; e += 4){
      int sA = srcs[e], sB = srcs[e+1], sC = srcs[e+2], sD = srcs[e+3];
      unsigned vA = *(const unsigned*)(in + (size_t)sA*lda + off);
      unsigned vB = *(const unsigned*)(in + (size_t)sB*lda + off);
      unsigned vC = *(const unsigned*)(in + (size_t)sC*lda + off);
      unsigned vD = *(const unsigned*)(in + (size_t)sD*lda + off);
      a0 += __uint_as_float(vA << 16); a1 += __uint_as_float(vA & 0xFFFF0000u);
      a0 += __uint_as_float(vB << 16); a1 += __uint_as_float(vB & 0xFFFF0000u);
      a0 += __uint_as_float(vC << 16); a1 += __uint_as_float(vC & 0xFFFF0000u);
      a0 += __uint_as_float(vD << 16); a1 += __uint_as_float(vD & 0xFFFF0000u);
    }
    for (; e < s1; ++e){
      int s = srcs[e];
      unsigned v = *(const unsigned*)(in + (size_t)s*lda + off);
      a0 += __uint_as_float(v << 16); a1 += __uint_as_float(v & 0xFFFF0000u);
    }
    float rc = rcnt[wid];
    bf16x2 o = {(bf_t)(a0*rc), (bf_t)(a1*rc)};
    *(bf16x2*)(out + (size_t)d*lda + r*DP + off) = o;
  }
}

// ---------------- MFMA GEMM: NT=128 column-split (col0 = blockIdx.y*128) ----------------
// Same code path that passes today for layer 0, now used for all layers via
// grid (391, O/128) -> 782 blocks for O=256 (removes the 391-block grid limit).
// acc = 32 AGPRs (vs 64 for NT=256): unified VGPR+AGPR need ~92 regs, fits the
// 3-blocks/CU budget (~85) with minimal spill. LDS padded to exactly 49152 B to
// pin the allocator's occupancy target at 3 blocks/CU (the spill-vs-occupancy
// model from rounds 9/11/12: budget = f(LDS-derived max blocks)).
template<int NT>
__global__ __launch_bounds__(512) void gemm_mfma2(const bf_t* __restrict__ A, int lda, int K,
                                                  const bf_t* __restrict__ Bt,
                                                  const float* __restrict__ bias,
                                                  float* __restrict__ C, int ldc, int O,
                                                  float* __restrict__ sums){
  constexpr int NI = NT/64;          // 2
  __shared__ uint4 lds4[(128 + NT)*8];   // 32768 B
  __shared__ uint4 ldspad[960];          // +15360 B -> total 49152 B: 3 blocks/CU
  __shared__ float colsum[2*NT];
  uint4* As4 = lds4;                 // [128][8] swizzled
  uint4* Bs4 = lds4 + 128*8;         // [NT][8] swizzled
  float* stage = (float*)lds4;       // epilogue: 32 x (NT+4) fp32
  if (K < 0) ((volatile float*)ldspad)[threadIdx.x] = 0.f;  // keep pad alive

  int tid = threadIdx.x;
  int lane = tid & 63;
  int wave = tid >> 6;               // 0..7
  int row0 = blockIdx.x*128;
  int col0 = blockIdx.y*NT;
  int mw = (wave & 1) << 6;
  int nw = (wave >> 1) * (NT/4);
  int l15 = lane & 15, quad = lane >> 4;
  f32x4 acc[4][NI] = {};
  uint4 av[2], bv[NI];
  int sl8u = tid & 7;
  int rbase = tid >> 3;              // 0..63
  int swz = rbase & 7;

  #pragma unroll
  for (int p = 0; p < 2; ++p){
    int gr = row0 + p*64 + rbase; if (gr >= NN) gr = NN - 1;
    av[p] = *(const uint4*)(A + (size_t)gr*lda + sl8u*8);
  }
  #pragma unroll
  for (int p = 0; p < NI; ++p)
    bv[p] = *(const uint4*)(Bt + (size_t)(col0 + p*64 + rbase)*K + sl8u*8);

  for (int k0 = 0; k0 < K; k0 += 64){
    __syncthreads();
    #pragma unroll
    for (int p = 0; p < 2; ++p)  As4[(p*64 + rbase)*8 + (sl8u ^ swz)] = av[p];
    #pragma unroll
    for (int p = 0; p < NI; ++p) Bs4[(p*64 + rbase)*8 + (sl8u ^ swz)] = bv[p];
    __syncthreads();
    if (k0 + 64 < K){
      int k1 = k0 + 64;
      #pragma unroll
      for (int p = 0; p < 2; ++p){
        int gr = row0 + p*64 + rbase; if (gr >= NN) gr = NN - 1;
        av[p] = *(const uint4*)(A + (size_t)gr*lda + k1 + sl8u*8);
      }
      #pragma unroll
      for (int p = 0; p < NI; ++p)
        bv[p] = *(const uint4*)(Bt + (size_t)(col0 + p*64 + rbase)*K + k1 + sl8u*8);
    }
    #pragma unroll
    for (int kk = 0; kk < 2; ++kk){
      bf16x8 af[4], bfv[NI];
      int ku = kk*4 + quad;
      #pragma unroll
      for (int mi = 0; mi < 4; ++mi){
        int R = mw + mi*16 + l15;
        af[mi] = *(const bf16x8*)&As4[R*8 + (ku ^ (R & 7))];
      }
      #pragma unroll
      for (int ni = 0; ni < NI; ++ni){
        int Rb = nw + ni*16 + l15;
        bfv[ni] = *(const bf16x8*)&Bs4[Rb*8 + (ku ^ (Rb & 7))];
      }
      #pragma unroll
      for (int mi = 0; mi < 4; ++mi)
        #pragma unroll
        for (int ni = 0; ni < NI; ++ni)
          acc[mi][ni] = __builtin_amdgcn_mfma_f32_16x16x32_bf16(af[mi], bfv[ni], acc[mi][ni], 0, 0, 0);
    }
  }

  // ---- epilogue: BN partials + staged coalesced C store ----
  __syncthreads();
  if (tid < 2*NT) colsum[tid] = 0.f;
  float bzv[NI];
  #pragma unroll
  for (int ni = 0; ni < NI; ++ni){
    int col = col0 + nw + ni*16 + l15;
    bzv[ni] = (col < O) ? bias[col] : 0.f;
  }
  __syncthreads();

  #pragma unroll
  for (int ni = 0; ni < NI; ++ni){
    int lcol = nw + ni*16 + l15;
    int col = col0 + lcol;
    if (col < O){
      float scol = 0.f, qcol = 0.f;
      #pragma unroll
      for (int mi = 0; mi < 4; ++mi){
        int rb = row0 + mw + mi*16 + quad*4;
        #pragma unroll
        for (int j = 0; j < 4; ++j){
          if (rb + j < NN){
            float v = acc[mi][ni][j] + bzv[ni];
            scol += v; qcol += v*v;
          }
        }
      }
      atomicAdd(&colsum[lcol], scol);
      atomicAdd(&colsum[NT + lcol], qcol);
    }
  }

  constexpr int STR = NT + 4;
  constexpr int TPR = NT/4;          // threads per row in store
  constexpr int RPR = 512/TPR;       // rows per store round
  int rl0 = tid / TPR;
  int colg = (tid % TPR)*4;
  #pragma unroll
  for (int c = 0; c < 4; ++c){
    __syncthreads();
    if ((wave & 1) == (c >> 1)){
      int base = (c & 1)*32;
      #pragma unroll
      for (int m2 = 0; m2 < 2; ++m2){
        int mi = (base >> 4) + m2;
        #pragma unroll
        for (int ni = 0; ni < NI; ++ni)
          #pragma unroll
          for (int j = 0; j < 4; ++j)
            stage[(mi*16 + quad*4 + j - base)*STR + nw + ni*16 + l15] = acc[mi][ni][j] + bzv[ni];
      }
    }
    __syncthreads();
    #pragma unroll
    for (int p = 0; p < 32/RPR; ++p){
      int rl = p*RPR + rl0;
      int gr = row0 + c*32 + rl;
      if (gr < NN)
        *(float4*)&C[(size_t)gr*ldc + col0 + colg] = *(const float4*)&stage[rl*STR + colg];
    }
  }

  __syncthreads();
  for (int c = tid; c < NT; c += 512){
    int col = col0 + c;
    if (col < O){
      unsafeAtomicAdd(&sums[col], colsum[c]);
      unsafeAtomicAdd(&sums[256 + col], colsum[NT + c]);
    }
  }
}

// ---------------- BN finalize ----------------
__global__ __launch_bounds__(256) void bn_finalize(const float* __restrict__ sums,
                                                   const float* __restrict__ g,
                                                   const float* __restrict__ bb,
                                                   float* __restrict__ scale,
                                                   float* __restrict__ shift, int dout){
  int c = threadIdx.x;
  if (c < dout){
    float mu = sums[c] * (1.0f/NN);
    float var = sums[256 + c] * (1.0f/NN) - mu*mu;
    float rstd = rsqrtf(fmaxf(var, 0.f) + EPSV);
    float s = rstd * g[c];
    scale[c] = s;
    shift[c] = bb[c] - mu*s;
  }
}

// BN apply fused with bf16 convert into Ab slice3 (next-layer layout)
template<int DPN>
__global__ __launch_bounds__(DPN) void bn_cvt(const float* __restrict__ C, int ldc, int O,
                                              const float* __restrict__ scale,
                                              const float* __restrict__ shift,
                                              bf_t* __restrict__ Ab, int ldan){
  int d = blockIdx.x, t = threadIdx.x;
  float v = 0.f;
  if (t < O) v = C[(size_t)d*ldc + t]*scale[t] + shift[t];
  Ab[(size_t)d*ldan + 3*DPN + t] = (bf_t)v;
}

// ---------------- global mean pool (batch sorted, bf16 input from Ab slice3) ----------------
__device__ __forceinline__ int lower_bound(const int* __restrict__ a, int v){
  int lo = 0, hi = NN;
  while (lo < hi){ int m = (lo+hi) >> 1; if (a[m] < v) lo = m+1; else hi = m; }
  return lo;
}

__global__ __launch_bounds__(256) void pool_kernel(const bf_t* __restrict__ H,
                                                   const int* __restrict__ batch,
                                                   float* __restrict__ pooled){
  int g = blockIdx.x, sl = blockIdx.y;
  int start = lower_bound(batch, g), end = lower_bound(batch, g+1);
  int len = end - start;
  float inv = 1.0f / (float)max(len, 1);
  int chunk = (len + 7) >> 3;
  int s0 = start + sl*chunk;
  int s1 = min(s0 + chunk, end);
  float s = 0.f;
  for (int n = s0; n < s1; ++n) s += (float)H[(size_t)n*1024 + threadIdx.x];
  if (s1 > s0) unsafeAtomicAdd(&pooled[g*256 + threadIdx.x], s * inv);
}

// ---------------- final MLP ----------------
__global__ __launch_bounds__(128) void final_kernel(const float* __restrict__ pooled,
                                                    const float* __restrict__ meta,
                                                    const float* __restrict__ w1,
                                                    const float* __restrict__ b1,
                                                    const float* __restrict__ w2,
                                                    const float* __restrict__ b2,
                                                    void* __restrict__ out,
                                                    const int* __restrict__ flag){
  int g = blockIdx.x;
  __shared__ float h1[100];
  __shared__ float red[128];
  int t = threadIdx.x;
  if (t < 100){
    float acc = b1[t];
    for (int k = 0; k < 256; ++k) acc += pooled[g*256 + k] * w1[k*100 + t];
    for (int k = 0; k < METAD; ++k) acc += meta[g*METAD + k] * w1[(256+k)*100 + t];
    h1[t] = acc;
  }
  __syncthreads();
  red[t] = (t < 100) ? h1[t] * w2[t] : 0.f;
  __syncthreads();
  for (int s = 64; s > 0; s >>= 1){
    if (t < s) red[t] += red[t + s];
    __syncthreads();
  }
  if (t == 0){
    float v = red[0] + b2[0];
    if (*flag) ((float*)out)[g] = v;
    else       ((__hip_bfloat16*)out)[g] = __float2bfloat16(v);
  }
}

// ---------------- launch ----------------
extern "C" void kernel_launch(void* const* d_in, const int* in_sizes, int n_in,
                              void* d_out, int out_size, void* d_ws, size_t ws_size,
                              hipStream_t stream){
  const void* x    = d_in[0];
  const int*  ei   = (const int*)d_in[2];
  const int*  et   = (const int*)d_in[3];
  const int*  batch= (const int*)d_in[5];

  // ---- workspace layout (float units) ----
  float* ws     = (float*)d_ws;
  int*   flag   = (int*)ws;                    // 16
  float* rcnt   = ws + 16;                     // 150000 -> 150016
  int*   cnt    = (int*)(ws + 150016);         // -> (pad 300032)
  int*   segoff = (int*)(ws + 300032);         // 150001 -> (pad 450048)
  int*   bsums  = (int*)(ws + 450048);         // 1024 -> 451072
  int*   srcs   = (int*)(ws + 451072);         // 800000 -> 1251072
  float* sums   = ws + 1251072;                // 512 -> 1251584
  float* scale  = ws + 1251584;                // 256
  float* shift  = ws + 1251840;                // 256
  float* pooled = ws + 1252096;                // 16384 -> 1268480
  float* bc     = ws + 1268480;                // 868
  float* gc_    = ws + 1269348;                // 868
  float* bbc    = ws + 1270216;                // 868
  float* metaf  = ws + 1271084;                // 2432
  float* w1f    = ws + 1273516;                // 29400
  float* b1f    = ws + 1302916;                // 100
  float* w2f    = ws + 1303016;                // 100
  float* b2f_   = ws + 1303116;                // 1 (pad 1303168)
  bf_t*  wt     = (bf_t*)(ws + 1303168);       // 720896 bf16 -> 1663616
  int*   cursor = (int*)(ws + 1663616);        // 150000 -> (pad 1813632)
  float* C      = ws + 1813632;                // 12800000 -> 14613632
  bf_t*  Ab     = (bf_t*)(ws + 14613632);      // 51200000 bf16 -> 40213632 (160.9 MB)

  const size_t wtoff[4] = {0, 65536, 196608, 458752};

  detect_kernel<<<1, 256, 0, stream>>>(x, flag);

  // ---- merged small-param convert (17 jobs, one launch) ----
  const int vsz[4]  = {100, 256, 256, 256};
  const int voff[4] = {0, 100, 356, 612};
  float *bfp[4], *gf[4], *bbf[4];
  CvtJobs J;
  int nj = 0;
  for (int l = 0; l < 4; ++l){
    bfp[l] = bc + voff[l]; gf[l] = gc_ + voff[l]; bbf[l] = bbc + voff[l];
    J.src[nj] = d_in[6 + l*5 + 2]; J.dst[nj] = bfp[l]; J.n[nj] = vsz[l]; nj++;
    J.src[nj] = d_in[6 + l*5 + 3]; J.dst[nj] = gf[l];  J.n[nj] = vsz[l]; nj++;
    J.src[nj] = d_in[6 + l*5 + 4]; J.dst[nj] = bbf[l]; J.n[nj] = vsz[l]; nj++;
  }
  J.src[nj] = d_in[4];  J.dst[nj] = metaf; J.n[nj] = GG*METAD; nj++;
  J.src[nj] = d_in[26]; J.dst[nj] = w1f;   J.n[nj] = 29400; nj++;
  J.src[nj] = d_in[27]; J.dst[nj] = b1f;   J.n[nj] = 100; nj++;
  J.src[nj] = d_in[28]; J.dst[nj] = w2f;   J.n[nj] = 100; nj++;
  J.src[nj] = d_in[29]; J.dst[nj] = b2f_;  J.n[nj] = 1; nj++;
  cvt_many<<<dim3(115, nj), 256, 0, stream>>>(J, flag);

  // ---- pack weights to bf16 [Op][4*DP] ----
  const int din[4] = {128, 100, 256, 256};
  const int dou[4] = {100, 256, 256, 256};
  const int DP[4]  = {128, 128, 256, 256};
  const int dplog[4] = {7, 7, 8, 8};
  const int Op[4]  = {128, 256, 256, 256};
  for (int l = 0; l < 4; ++l){
    int total = Op[l] << (dplog[l] + 2);
    pack_w<<<total/256, 256, 0, stream>>>(d_in[6 + l*5 + 0], d_in[6 + l*5 + 1],
                                          wt + wtoff[l], din[l], dou[l], dplog[l], flag);
  }

  // ---- CSR build ----
  hipMemsetAsync(cnt, 0, NSEG*sizeof(int), stream);
  counti_kernel<<<(EE+255)/256, 256, 0, stream>>>(ei, et, cnt);
  rcnt_kernel<<<(NSEG+255)/256, 256, 0, stream>>>(cnt, rcnt);
  int nb = (NSEG + 255)/256;
  scan1_kernel<<<nb, 256, 0, stream>>>(cnt, segoff, bsums);
  scan2_kernel<<<1, 256, 0, stream>>>(bsums, nb);
  scan3_kernel<<<nb, 256, 0, stream>>>(segoff, bsums);
  curinit_kernel<<<nb, 256, 0, stream>>>(segoff, cursor);
  place_kernel<<<(EE+255)/256, 256, 0, stream>>>(ei, et, cursor, srcs);

  // ---- layer 0 input ----
  cvt_x<<<NN, 128, 0, stream>>>(x, Ab, flag);

  const int lda[4] = {512, 512, 1024, 1024};
  int aggBlocks = (NSEG + 3)/4;   // 4 waves per 256-block
  for (int l = 0; l < 4; ++l){
    int O = dou[l];
    if (DP[l] == 128)
      aggregate_wave<128><<<aggBlocks, 256, 0, stream>>>(Ab, lda[l], segoff, srcs, rcnt, Ab);
    else
      aggregate_wave<256><<<aggBlocks, 256, 0, stream>>>(Ab, lda[l], segoff, srcs, rcnt, Ab);

    hipMemsetAsync(sums, 0, 512*sizeof(float), stream);
    dim3 g2(391, Op[l]/128);
    gemm_mfma2<128><<<g2, 512, 0, stream>>>(Ab, lda[l], 4*DP[l], wt + wtoff[l], bfp[l],
                                            C, Op[l], O, sums);

    bn_finalize<<<1, 256, 0, stream>>>(sums, gf[l], bbf[l], scale, shift, O);

    int DPN = (l < 3) ? DP[l+1] : 256;
    int ldan = (l < 3) ? lda[l+1] : 1024;
    if (DPN == 128)
      bn_cvt<128><<<NN, 128, 0, stream>>>(C, Op[l], O, scale, shift, Ab, ldan);
    else
      bn_cvt<256><<<NN, 256, 0, stream>>>(C, Op[l], O, scale, shift, Ab, ldan);
  }

  hipMemsetAsync(pooled, 0, (size_t)GG*256*sizeof(float), stream);
  pool_kernel<<<dim3(GG, 8), 256, 0, stream>>>(Ab + 768, batch, pooled);
  final_kernel<<<GG, 128, 0, stream>>>(pooled, metaf, w1f, b1f, w2f, b2f_, d_out, flag);
}

// Round 14
// 937.376 us; speedup vs baseline: 1.2270x; 1.2270x over previous
//
#include <hip/hip_runtime.h>
#include <hip/hip_bf16.h>

#define NN 50000
#define EE 800000
#define GG 64
#define RR 3
#define METAD 38
#define NSEG (RR*NN)
#define EPSV 1e-5f

typedef __bf16 bf_t;
typedef __attribute__((ext_vector_type(8))) __bf16 bf16x8;
typedef __attribute__((ext_vector_type(4))) __bf16 bf16x4;
typedef __attribute__((ext_vector_type(2))) __bf16 bf16x2;
typedef __attribute__((ext_vector_type(4))) float f32x4;
typedef __attribute__((address_space(1))) void gas_t;
typedef __attribute__((address_space(3))) void las_t;

__device__ __forceinline__ float loadf(const void* p, size_t i, int flag){
  return flag ? ((const float*)p)[i] : (float)(((const bf_t*)p)[i]);
}

// ---------------- dtype detector: fp32 (1) vs bf16 (0) ----------------
__global__ __launch_bounds__(256) void detect_kernel(const void* __restrict__ xraw,
                                                     int* __restrict__ flag){
  __shared__ int found;
  if (threadIdx.x == 0) found = 0;
  __syncthreads();
  const unsigned short* u = (const unsigned short*)xraw;
  for (int i = threadIdx.x; i < 65536; i += 256){
    int e = (u[i] >> 7) & 0xFF;
    if (e >= 0xF0) found = 1;
  }
  __syncthreads();
  if (threadIdx.x == 0) *flag = found;
}

// ---------------- merged small-param convert ----------------
struct CvtJobs {
  const void* src[17];
  float* dst[17];
  int n[17];
};

__global__ __launch_bounds__(256) void cvt_many(CvtJobs j, const int* __restrict__ flag){
  int job = blockIdx.y;
  int i = blockIdx.x*256 + threadIdx.x;
  if (i < j.n[job]) j.dst[job][i] = loadf(j.src[job], i, *flag);
}

// ---------------- pack weights: WbT[o][r*DP+i] = W[r][i][o] (bf16, zero-padded) ----------------
__global__ __launch_bounds__(256) void pack_w(const void* __restrict__ W,
                                              const void* __restrict__ R,
                                              bf_t* __restrict__ out,
                                              int D, int O, int dplog,
                                              const int* __restrict__ flag){
  int id = blockIdx.x*256 + threadIdx.x;
  int DP4 = 1 << (dplog + 2);
  int o = id >> (dplog + 2);
  int k = id & (DP4 - 1);
  int r = k >> dplog;
  int i = k & ((1 << dplog) - 1);
  float v = 0.f;
  int fl = *flag;
  if (i < D && o < O){
    if (r < 3) v = loadf(W, ((size_t)r*D + i)*O + o, fl);
    else       v = loadf(R, (size_t)i*O + o, fl);
  }
  out[(size_t)o*DP4 + k] = (bf_t)v;
}

// ---------------- CSR build ----------------
__global__ __launch_bounds__(256) void counti_kernel(const int* __restrict__ ei,
                                                     const int* __restrict__ et,
                                                     int* __restrict__ cnt){
  int e = blockIdx.x*256 + threadIdx.x;
  if (e < EE) atomicAdd(&cnt[et[e]*NN + ei[EE + e]], 1);
}

__global__ __launch_bounds__(256) void rcnt_kernel(const int* __restrict__ cnt,
                                                   float* __restrict__ rcnt){
  int i = blockIdx.x*256 + threadIdx.x;
  if (i < NSEG) rcnt[i] = 1.0f / (float)max(cnt[i], 1);
}

__global__ __launch_bounds__(256) void scan1_kernel(const int* __restrict__ cnt,
                                                    int* __restrict__ segoff,
                                                    int* __restrict__ bsums){
  __shared__ int sh[256];
  int i = blockIdx.x*256 + threadIdx.x;
  int v = (i < NSEG) ? cnt[i] : 0;
  sh[threadIdx.x] = v;
  __syncthreads();
  for (int off = 1; off < 256; off <<= 1){
    int t = 0;
    if (threadIdx.x >= off) t = sh[threadIdx.x - off];
    __syncthreads();
    if (threadIdx.x >= off) sh[threadIdx.x] += t;
    __syncthreads();
  }
  if (i < NSEG) segoff[i] = sh[threadIdx.x] - v;
  if (threadIdx.x == 255) bsums[blockIdx.x] = sh[255];
}

__global__ __launch_bounds__(256) void scan2_kernel(int* __restrict__ bsums, int nb){
  __shared__ int sh[256];
  __shared__ int carry;
  if (threadIdx.x == 0) carry = 0;
  __syncthreads();
  for (int base = 0; base < nb; base += 256){
    int i = base + threadIdx.x;
    int v = (i < nb) ? bsums[i] : 0;
    sh[threadIdx.x] = v;
    __syncthreads();
    for (int off = 1; off < 256; off <<= 1){
      int t = 0;
      if (threadIdx.x >= off) t = sh[threadIdx.x - off];
      __syncthreads();
      if (threadIdx.x >= off) sh[threadIdx.x] += t;
      __syncthreads();
    }
    if (i < nb) bsums[i] = sh[threadIdx.x] - v + carry;
    __syncthreads();
    if (threadIdx.x == 0) carry += sh[255];
    __syncthreads();
  }
}

__global__ __launch_bounds__(256) void scan3_kernel(int* __restrict__ segoff,
                                                    const int* __restrict__ bsums){
  int i = blockIdx.x*256 + threadIdx.x;
  if (i < NSEG) segoff[i] += bsums[blockIdx.x];
  if (i == 0) segoff[NSEG] = EE;
}

__global__ __launch_bounds__(256) void curinit_kernel(const int* __restrict__ segoff,
                                                      int* __restrict__ cursor){
  int i = blockIdx.x*256 + threadIdx.x;
  if (i < NSEG) cursor[i] = segoff[i];
}

__global__ __launch_bounds__(256) void place_kernel(const int* __restrict__ ei,
                                                    const int* __restrict__ et,
                                                    int* __restrict__ cursor,
                                                    int* __restrict__ srcs){
  int e = blockIdx.x*256 + threadIdx.x;
  if (e < EE){
    int seg = et[e]*NN + ei[EE + e];
    int pos = atomicAdd(&cursor[seg], 1);
    srcs[pos] = ei[e];
  }
}

// ---------------- x -> Ab slice3 (layer0, D=DP=128, lda=512) ----------------
__global__ __launch_bounds__(128) void cvt_x(const void* __restrict__ x,
                                             bf_t* __restrict__ Ab,
                                             const int* __restrict__ flag){
  int d = blockIdx.x, t = threadIdx.x;
  Ab[(size_t)d*512 + 384 + t] = (bf_t)loadf(x, (size_t)d*128 + t, *flag);
}

// ------- wave-per-segment CSR gather mean: Y[d][r*DP+c] = rcnt * sum h[src][c] -------
template<int DP>
__global__ __launch_bounds__(256) void aggregate_wave(const bf_t* __restrict__ Ab, int lda,
                                                      const int* __restrict__ segoff,
                                                      const int* __restrict__ srcs,
                                                      const float* __restrict__ rcnt,
                                                      bf_t* __restrict__ out){
  int wid = (blockIdx.x*256 + threadIdx.x) >> 6;
  if (wid >= NSEG) return;
  int lane = threadIdx.x & 63;
  int r = wid / NN;
  int d = wid - r*NN;
  int s0 = segoff[wid], s1 = segoff[wid + 1];
  const bf_t* in = Ab + 3*DP;

  if (DP == 256){
    float a0=0.f, a1=0.f, a2=0.f, a3=0.f;
    const int off = lane*4;
    int e = s0;
    for (; e + 4 <= s1; e += 4){
      int sA = srcs[e], sB = srcs[e+1], sC = srcs[e+2], sD = srcs[e+3];
      uint2 vA = *(const uint2*)(in + (size_t)sA*lda + off);
      uint2 vB = *(const uint2*)(in + (size_t)sB*lda + off);
      uint2 vC = *(const uint2*)(in + (size_t)sC*lda + off);
      uint2 vD = *(const uint2*)(in + (size_t)sD*lda + off);
      a0 += __uint_as_float(vA.x << 16); a1 += __uint_as_float(vA.x & 0xFFFF0000u);
      a2 += __uint_as_float(vA.y << 16); a3 += __uint_as_float(vA.y & 0xFFFF0000u);
      a0 += __uint_as_float(vB.x << 16); a1 += __uint_as_float(vB.x & 0xFFFF0000u);
      a2 += __uint_as_float(vB.y << 16); a3 += __uint_as_float(vB.y & 0xFFFF0000u);
      a0 += __uint_as_float(vC.x << 16); a1 += __uint_as_float(vC.x & 0xFFFF0000u);
      a2 += __uint_as_float(vC.y << 16); a3 += __uint_as_float(vC.y & 0xFFFF0000u);
      a0 += __uint_as_float(vD.x << 16); a1 += __uint_as_float(vD.x & 0xFFFF0000u);
      a2 += __uint_as_float(vD.y << 16); a3 += __uint_as_float(vD.y & 0xFFFF0000u);
    }
    for (; e < s1; ++e){
      int s = srcs[e];
      uint2 v = *(const uint2*)(in + (size_t)s*lda + off);
      a0 += __uint_as_float(v.x << 16); a1 += __uint_as_float(v.x & 0xFFFF0000u);
      a2 += __uint_as_float(v.y << 16); a3 += __uint_as_float(v.y & 0xFFFF0000u);
    }
    float rc = rcnt[wid];
    bf16x4 o = {(bf_t)(a0*rc), (bf_t)(a1*rc), (bf_t)(a2*rc), (bf_t)(a3*rc)};
    *(bf16x4*)(out + (size_t)d*lda + r*DP + off) = o;
  } else {
    float a0=0.f, a1=0.f;
    const int off = lane*2;
    int e = s0;
    for (; e + 4 <= s1; e += 4){
      int sA = srcs[e], sB = srcs[e+1], sC = srcs[e+2], sD = srcs[e+3];
      unsigned vA = *(const unsigned*)(in + (size_t)sA*lda + off);
      unsigned vB = *(const unsigned*)(in + (size_t)sB*lda + off);
      unsigned vC = *(const unsigned*)(in + (size_t)sC*lda + off);
      unsigned vD = *(const unsigned*)(in + (size_t)sD*lda + off);
      a0 += __uint_as_float(vA << 16); a1 += __uint_as_float(vA & 0xFFFF0000u);
      a0 += __uint_as_float(vB << 16); a1 += __uint_as_float(vB & 0xFFFF0000u);
      a0 += __uint_as_float(vC << 16); a1 += __uint_as_float(vC & 0xFFFF0000u);
      a0 += __uint_as_float(vD << 16); a1 += __uint_as_float(vD & 0xFFFF0000u);
    }
    for (; e < s1; ++e){
      int s = srcs[e];
      unsigned v = *(const unsigned*)(in + (size_t)s*lda + off);
      a0 += __uint_as_float(v << 16); a1 += __uint_as_float(v & 0xFFFF0000u);
    }
    float rc = rcnt[wid];
    bf16x2 o = {(bf_t)(a0*rc), (bf_t)(a1*rc)};
    *(bf16x2*)(out + (size_t)d*lda + r*DP + off) = o;
  }
}

// ---------------- MFMA GEMM: NT=128 col-split + global_load_lds staging ----------------
// Staging via __builtin_amdgcn_global_load_lds width=16 (m97 pattern): zero data
// VGPRs for staging, no cross-iteration live ranges except the AGPR accumulators.
// This removes the register pressure that caused the allocator-spill WRITE bloat
// (r11: 202 MB, r13: 313 MB at VGPR_Count 60/40). LDS row-major stride 8 uint4:
// wave w, chunk a=2w+c, lane i -> row 8a+i/8, kchunk i%8 -> lds offset = lane*16,
// satisfying the wave-uniform-base + lane*16 contract. Swizzle dropped (r11 showed
// bank conflicts are off the critical path here). m97 single-buffer 2-barrier loop.
template<int NT>
__global__ __launch_bounds__(512) void gemm_mfma2(const bf_t* __restrict__ A, int lda, int K,
                                                  const bf_t* __restrict__ Bt,
                                                  const float* __restrict__ bias,
                                                  float* __restrict__ C, int ldc, int O,
                                                  float* __restrict__ sums){
  constexpr int NI = NT/64;              // 2 (only <128> is instantiated)
  __shared__ uint4 lds4[(128 + NT)*8];   // 32768 B
  __shared__ uint4 ldspad[960];          // pad -> 49152 B total (pins 3 blocks/CU target)
  __shared__ float colsum[2*NT];
  uint4* As4 = lds4;                     // [128][8] row-major
  uint4* Bs4 = lds4 + 128*8;             // [NT][8] row-major
  float* stage = (float*)lds4;           // epilogue overlay
  if (K < 0) ((volatile float*)ldspad)[threadIdx.x] = 0.f;  // keep pad alive

  int tid = threadIdx.x;
  int lane = tid & 63;
  int wave = tid >> 6;                   // 0..7
  int row0 = blockIdx.x*128;
  int col0 = blockIdx.y*NT;
  int mw = (wave & 1) << 6;
  int nw = (wave >> 1) * (NT/4);
  int l15 = lane & 15, quad = lane >> 4;
  f32x4 acc[4][NI] = {};

  // staging geometry: chunks a0=2w, a1=2w+1; lane i covers (row 8a+i/8, kchunk i%8)
  int lrow = lane >> 3;                  // 0..7
  int lk8  = (lane & 7) * 8;             // bf16 k-offset within 64
  int ca0 = wave*2, ca1 = wave*2 + 1;
  int gra0 = row0 + ca0*8 + lrow; if (gra0 >= NN) gra0 = NN - 1;
  int gra1 = row0 + ca1*8 + lrow; if (gra1 >= NN) gra1 = NN - 1;
  const bf_t* Ar0 = A + (size_t)gra0*lda + lk8;
  const bf_t* Ar1 = A + (size_t)gra1*lda + lk8;
  const bf_t* Br0 = Bt + (size_t)(col0 + ca0*8 + lrow)*K + lk8;
  const bf_t* Br1 = Bt + (size_t)(col0 + ca1*8 + lrow)*K + lk8;
  uint4* AsD0 = As4 + ca0*64;            // wave-uniform LDS bases
  uint4* AsD1 = As4 + ca1*64;
  uint4* BsD0 = Bs4 + ca0*64;
  uint4* BsD1 = Bs4 + ca1*64;

  // prologue: issue tile 0
  __builtin_amdgcn_global_load_lds((gas_t*)Ar0, (las_t*)AsD0, 16, 0, 0);
  __builtin_amdgcn_global_load_lds((gas_t*)Ar1, (las_t*)AsD1, 16, 0, 0);
  __builtin_amdgcn_global_load_lds((gas_t*)Br0, (las_t*)BsD0, 16, 0, 0);
  __builtin_amdgcn_global_load_lds((gas_t*)Br1, (las_t*)BsD1, 16, 0, 0);

  int niter = K >> 6;
  for (int i = 0; i < niter; ++i){
    __syncthreads();                     // vmcnt drained -> tile i resident
    #pragma unroll
    for (int kk = 0; kk < 2; ++kk){
      bf16x8 af[4], bfv[NI];
      int ku = kk*4 + quad;
      #pragma unroll
      for (int mi = 0; mi < 4; ++mi){
        int R = mw + mi*16 + l15;
        af[mi] = *(const bf16x8*)&As4[R*8 + ku];
      }
      #pragma unroll
      for (int ni = 0; ni < NI; ++ni){
        int Rb = nw + ni*16 + l15;
        bfv[ni] = *(const bf16x8*)&Bs4[Rb*8 + ku];
      }
      #pragma unroll
      for (int mi = 0; mi < 4; ++mi)
        #pragma unroll
        for (int ni = 0; ni < NI; ++ni)
          acc[mi][ni] = __builtin_amdgcn_mfma_f32_16x16x32_bf16(af[mi], bfv[ni], acc[mi][ni], 0, 0, 0);
    }
    __syncthreads();                     // all reads done before overwrite
    if (i + 1 < niter){
      int k1 = (i + 1) << 6;             // bf16 elements
      __builtin_amdgcn_global_load_lds((gas_t*)(Ar0 + k1), (las_t*)AsD0, 16, 0, 0);
      __builtin_amdgcn_global_load_lds((gas_t*)(Ar1 + k1), (las_t*)AsD1, 16, 0, 0);
      __builtin_amdgcn_global_load_lds((gas_t*)(Br0 + k1), (las_t*)BsD0, 16, 0, 0);
      __builtin_amdgcn_global_load_lds((gas_t*)(Br1 + k1), (las_t*)BsD1, 16, 0, 0);
    }
  }

  // ---- epilogue: BN partials + staged coalesced C store (verbatim r13) ----
  __syncthreads();
  if (tid < 2*NT) colsum[tid] = 0.f;
  float bzv[NI];
  #pragma unroll
  for (int ni = 0; ni < NI; ++ni){
    int col = col0 + nw + ni*16 + l15;
    bzv[ni] = (col < O) ? bias[col] : 0.f;
  }
  __syncthreads();

  #pragma unroll
  for (int ni = 0; ni < NI; ++ni){
    int lcol = nw + ni*16 + l15;
    int col = col0 + lcol;
    if (col < O){
      float scol = 0.f, qcol = 0.f;
      #pragma unroll
      for (int mi = 0; mi < 4; ++mi){
        int rb = row0 + mw + mi*16 + quad*4;
        #pragma unroll
        for (int j = 0; j < 4; ++j){
          if (rb + j < NN){
            float v = acc[mi][ni][j] + bzv[ni];
            scol += v; qcol += v*v;
          }
        }
      }
      atomicAdd(&colsum[lcol], scol);
      atomicAdd(&colsum[NT + lcol], qcol);
    }
  }

  constexpr int STR = NT + 4;
  constexpr int TPR = NT/4;          // threads per row in store
  constexpr int RPR = 512/TPR;       // rows per store round
  int rl0 = tid / TPR;
  int colg = (tid % TPR)*4;
  #pragma unroll
  for (int c = 0; c < 4; ++c){
    __syncthreads();
    if ((wave & 1) == (c >> 1)){
      int base = (c & 1)*32;
      #pragma unroll
      for (int m2 = 0; m2 < 2; ++m2){
        int mi = (base >> 4) + m2;
        #pragma unroll
        for (int ni = 0; ni < NI; ++ni)
          #pragma unroll
          for (int j = 0; j < 4; ++j)
            stage[(mi*16 + quad*4 + j - base)*STR + nw + ni*16 + l15] = acc[mi][ni][j] + bzv[ni];
      }
    }
    __syncthreads();
    #pragma unroll
    for (int p = 0; p < 32/RPR; ++p){
      int rl = p*RPR + rl0;
      int gr = row0 + c*32 + rl;
      if (gr < NN)
        *(float4*)&C[(size_t)gr*ldc + col0 + colg] = *(const float4*)&stage[rl*STR + colg];
    }
  }

  __syncthreads();
  for (int c = tid; c < NT; c += 512){
    int col = col0 + c;
    if (col < O){
      unsafeAtomicAdd(&sums[col], colsum[c]);
      unsafeAtomicAdd(&sums[256 + col], colsum[NT + c]);
    }
  }
}

// ---------------- BN finalize ----------------
__global__ __launch_bounds__(256) void bn_finalize(const float* __restrict__ sums,
                                                   const float* __restrict__ g,
                                                   const float* __restrict__ bb,
                                                   float* __restrict__ scale,
                                                   float* __restrict__ shift, int dout){
  int c = threadIdx.x;
  if (c < dout){
    float mu = sums[c] * (1.0f/NN);
    float var = sums[256 + c] * (1.0f/NN) - mu*mu;
    float rstd = rsqrtf(fmaxf(var, 0.f) + EPSV);
    float s = rstd * g[c];
    scale[c] = s;
    shift[c] = bb[c] - mu*s;
  }
}

// BN apply fused with bf16 convert into Ab slice3 (next-layer layout)
template<int DPN>
__global__ __launch_bounds__(DPN) void bn_cvt(const float* __restrict__ C, int ldc, int O,
                                              const float* __restrict__ scale,
                                              const float* __restrict__ shift,
                                              bf_t* __restrict__ Ab, int ldan){
  int d = blockIdx.x, t = threadIdx.x;
  float v = 0.f;
  if (t < O) v = C[(size_t)d*ldc + t]*scale[t] + shift[t];
  Ab[(size_t)d*ldan + 3*DPN + t] = (bf_t)v;
}

// ---------------- global mean pool (batch sorted, bf16 input from Ab slice3) ----------------
__device__ __forceinline__ int lower_bound(const int* __restrict__ a, int v){
  int lo = 0, hi = NN;
  while (lo < hi){ int m = (lo+hi) >> 1; if (a[m] < v) lo = m+1; else hi = m; }
  return lo;
}

__global__ __launch_bounds__(256) void pool_kernel(const bf_t* __restrict__ H,
                                                   const int* __restrict__ batch,
                                                   float* __restrict__ pooled){
  int g = blockIdx.x, sl = blockIdx.y;
  int start = lower_bound(batch, g), end = lower_bound(batch, g+1);
  int len = end - start;
  float inv = 1.0f / (float)max(len, 1);
  int chunk = (len + 7) >> 3;
  int s0 = start + sl*chunk;
  int s1 = min(s0 + chunk, end);
  float s = 0.f;
  for (int n = s0; n < s1; ++n) s += (float)H[(size_t)n*1024 + threadIdx.x];
  if (s1 > s0) unsafeAtomicAdd(&pooled[g*256 + threadIdx.x], s * inv);
}

// ---------------- final MLP ----------------
__global__ __launch_bounds__(128) void final_kernel(const float* __restrict__ pooled,
                                                    const float* __restrict__ meta,
                                                    const float* __restrict__ w1,
                                                    const float* __restrict__ b1,
                                                    const float* __restrict__ w2,
                                                    const float* __restrict__ b2,
                                                    void* __restrict__ out,
                                                    const int* __restrict__ flag){
  int g = blockIdx.x;
  __shared__ float h1[100];
  __shared__ float red[128];
  int t = threadIdx.x;
  if (t < 100){
    float acc = b1[t];
    for (int k = 0; k < 256; ++k) acc += pooled[g*256 + k] * w1[k*100 + t];
    for (int k = 0; k < METAD; ++k) acc += meta[g*METAD + k] * w1[(256+k)*100 + t];
    h1[t] = acc;
  }
  __syncthreads();
  red[t] = (t < 100) ? h1[t] * w2[t] : 0.f;
  __syncthreads();
  for (int s = 64; s > 0; s >>= 1){
    if (t < s) red[t] += red[t + s];
    __syncthreads();
  }
  if (t == 0){
    float v = red[0] + b2[0];
    if (*flag) ((float*)out)[g] = v;
    else       ((__hip_bfloat16*)out)[g] = __float2bfloat16(v);
  }
}

// ---------------- launch ----------------
extern "C" void kernel_launch(void* const* d_in, const int* in_sizes, int n_in,
                              void* d_out, int out_size, void* d_ws, size_t ws_size,
                              hipStream_t stream){
  const void* x    = d_in[0];
  const int*  ei   = (const int*)d_in[2];
  const int*  et   = (const int*)d_in[3];
  const int*  batch= (const int*)d_in[5];

  // ---- workspace layout (float units) ----
  float* ws     = (float*)d_ws;
  int*   flag   = (int*)ws;                    // 16
  float* rcnt   = ws + 16;                     // 150000 -> 150016
  int*   cnt    = (int*)(ws + 150016);         // -> (pad 300032)
  int*   segoff = (int*)(ws + 300032);         // 150001 -> (pad 450048)
  int*   bsums  = (int*)(ws + 450048);         // 1024 -> 451072
  int*   srcs   = (int*)(ws + 451072);         // 800000 -> 1251072
  float* sums   = ws + 1251072;                // 512 -> 1251584
  float* scale  = ws + 1251584;                // 256
  float* shift  = ws + 1251840;                // 256
  float* pooled = ws + 1252096;                // 16384 -> 1268480
  float* bc     = ws + 1268480;                // 868
  float* gc_    = ws + 1269348;                // 868
  float* bbc    = ws + 1270216;                // 868
  float* metaf  = ws + 1271084;                // 2432
  float* w1f    = ws + 1273516;                // 29400
  float* b1f    = ws + 1302916;                // 100
  float* w2f    = ws + 1303016;                // 100
  float* b2f_   = ws + 1303116;                // 1 (pad 1303168)
  bf_t*  wt     = (bf_t*)(ws + 1303168);       // 720896 bf16 -> 1663616
  int*   cursor = (int*)(ws + 1663616);        // 150000 -> (pad 1813632)
  float* C      = ws + 1813632;                // 12800000 -> 14613632
  bf_t*  Ab     = (bf_t*)(ws + 14613632);      // 51200000 bf16 -> 40213632 (160.9 MB)

  const size_t wtoff[4] = {0, 65536, 196608, 458752};

  detect_kernel<<<1, 256, 0, stream>>>(x, flag);

  // ---- merged small-param convert (17 jobs, one launch) ----
  const int vsz[4]  = {100, 256, 256, 256};
  const int voff[4] = {0, 100, 356, 612};
  float *bfp[4], *gf[4], *bbf[4];
  CvtJobs J;
  int nj = 0;
  for (int l = 0; l < 4; ++l){
    bfp[l] = bc + voff[l]; gf[l] = gc_ + voff[l]; bbf[l] = bbc + voff[l];
    J.src[nj] = d_in[6 + l*5 + 2]; J.dst[nj] = bfp[l]; J.n[nj] = vsz[l]; nj++;
    J.src[nj] = d_in[6 + l*5 + 3]; J.dst[nj] = gf[l];  J.n[nj] = vsz[l]; nj++;
    J.src[nj] = d_in[6 + l*5 + 4]; J.dst[nj] = bbf[l]; J.n[nj] = vsz[l]; nj++;
  }
  J.src[nj] = d_in[4];  J.dst[nj] = metaf; J.n[nj] = GG*METAD; nj++;
  J.src[nj] = d_in[26]; J.dst[nj] = w1f;   J.n[nj] = 29400; nj++;
  J.src[nj] = d_in[27]; J.dst[nj] = b1f;   J.n[nj] = 100; nj++;
  J.src[nj] = d_in[28]; J.dst[nj] = w2f;   J.n[nj] = 100; nj++;
  J.src[nj] = d_in[29]; J.dst[nj] = b2f_;  J.n[nj] = 1; nj++;
  cvt_many<<<dim3(115, nj), 256, 0, stream>>>(J, flag);

  // ---- pack weights to bf16 [Op][4*DP] ----
  const int din[4] = {128, 100, 256, 256};
  const int dou[4] = {100, 256, 256, 256};
  const int DP[4]  = {128, 128, 256, 256};
  const int dplog[4] = {7, 7, 8, 8};
  const int Op[4]  = {128, 256, 256, 256};
  for (int l = 0; l < 4; ++l){
    int total = Op[l] << (dplog[l] + 2);
    pack_w<<<total/256, 256, 0, stream>>>(d_in[6 + l*5 + 0], d_in[6 + l*5 + 1],
                                          wt + wtoff[l], din[l], dou[l], dplog[l], flag);
  }

  // ---- CSR build ----
  hipMemsetAsync(cnt, 0, NSEG*sizeof(int), stream);
  counti_kernel<<<(EE+255)/256, 256, 0, stream>>>(ei, et, cnt);
  rcnt_kernel<<<(NSEG+255)/256, 256, 0, stream>>>(cnt, rcnt);
  int nb = (NSEG + 255)/256;
  scan1_kernel<<<nb, 256, 0, stream>>>(cnt, segoff, bsums);
  scan2_kernel<<<1, 256, 0, stream>>>(bsums, nb);
  scan3_kernel<<<nb, 256, 0, stream>>>(segoff, bsums);
  curinit_kernel<<<nb, 256, 0, stream>>>(segoff, cursor);
  place_kernel<<<(EE+255)/256, 256, 0, stream>>>(ei, et, cursor, srcs);

  // ---- layer 0 input ----
  cvt_x<<<NN, 128, 0, stream>>>(x, Ab, flag);

  const int lda[4] = {512, 512, 1024, 1024};
  int aggBlocks = (NSEG + 3)/4;   // 4 waves per 256-block
  for (int l = 0; l < 4; ++l){
    int O = dou[l];
    if (DP[l] == 128)
      aggregate_wave<128><<<aggBlocks, 256, 0, stream>>>(Ab, lda[l], segoff, srcs, rcnt, Ab);
    else
      aggregate_wave<256><<<aggBlocks, 256, 0, stream>>>(Ab, lda[l], segoff, srcs, rcnt, Ab);

    hipMemsetAsync(sums, 0, 512*sizeof(float), stream);
    dim3 g2(391, Op[l]/128);
    gemm_mfma2<128><<<g2, 512, 0, stream>>>(Ab, lda[l], 4*DP[l], wt + wtoff[l], bfp[l],
                                            C, Op[l], O, sums);

    bn_finalize<<<1, 256, 0, stream>>>(sums, gf[l], bbf[l], scale, shift, O);

    int DPN = (l < 3) ? DP[l+1] : 256;
    int ldan = (l < 3) ? lda[l+1] : 1024;
    if (DPN == 128)
      bn_cvt<128><<<NN, 128, 0, stream>>>(C, Op[l], O, scale, shift, Ab, ldan);
    else
      bn_cvt<256><<<NN, 256, 0, stream>>>(C, Op[l], O, scale, shift, Ab, ldan);
  }

  hipMemsetAsync(pooled, 0, (size_t)GG*256*sizeof(float), stream);
  pool_kernel<<<dim3(GG, 8), 256, 0, stream>>>(Ab + 768, batch, pooled);
  final_kernel<<<GG, 128, 0, stream>>>(pooled, metaf, w1f, b1f, w2f, b2f_, d_out, flag);
}